// Round 3
// baseline (3617.206 us; speedup 1.0000x reference)
//
#include <hip/hip_runtime.h>
#include <hip/hip_bf16.h>

typedef __attribute__((ext_vector_type(8))) short short8;
typedef __attribute__((ext_vector_type(4))) float f32x4;

#define SEQ 40
#define IN_DIM 24
#define NKER 36
#define ENC 128
#define HID 64
#define NSTEPS 50
#define BTOT 65536

// float-element offsets into d_ws
#define WS_FLAG 0      // 1.0 = inputs are bf16, 0.0 = inputs are f32
#define WS_DT   1
#define WS_CW   16                     // [36][3][24] conv_w f32
#define WS_CB   2608                   // [36]
#define WS_E1T  4096                   // [1440][128] enc1_w transposed f32
#define WS_E1B  188416                 // [128]
#define WS_EW   188544                 // [64][128] enc2_w f32
#define WS_EB   196736                 // [64]
#define WS_W1H  196800                 // [64][64] bf16 hi (2048 f)
#define WS_W1L  198848                 // [64][64] bf16 lo
#define WS_W2H  200896
#define WS_W2L  202944
#define WS_R1H  204992                 // [32][64] bf16 hi (1024 f)
#define WS_R1L  206016
#define WS_O1B  207040                 // [64] f32
#define WS_O2B  207104                 // [64] f32
#define WS_R1B  207168                 // [32] f32
#define WS_R2W  207200                 // [32] f32
#define WS_R2B  207232                 // [1]  f32
#define WS_TH0  262144                 // [B][64] f32 theta0

__device__ __forceinline__ float bflo(unsigned int u){
  union { unsigned int i; float f; } v; v.i = u << 16; return v.f;
}
__device__ __forceinline__ float bfhi(unsigned int u){
  union { unsigned int i; float f; } v; v.i = u & 0xffff0000u; return v.f;
}
__device__ __forceinline__ unsigned short f2bf(float f){   // RNE
  union { float f; unsigned int u; } v; v.f = f;
  unsigned int r = (v.u + 0x7FFFu + ((v.u >> 16) & 1u)) >> 16;
  return (unsigned short)r;
}
__device__ __forceinline__ float bf2f(unsigned short s){
  union { unsigned int u; float f; } v; v.u = ((unsigned int)s) << 16; return v.f;
}
__device__ __forceinline__ float tanh_fast(float x){
  float ax = fabsf(x);
  float e  = __expf(-2.0f * ax);
  float t  = (1.0f - e) * __builtin_amdgcn_rcpf(1.0f + e);
  union { float f; unsigned int u; } vx, vt;
  vx.f = x; vt.f = t; vt.u |= (vx.u & 0x80000000u);
  return vt.f;
}

// ---------------- detector: input dtype sniff + dt ----------------
__global__ void k_detect(const void* __restrict__ x, const void* __restrict__ t_span,
                         float* __restrict__ ws){
  const unsigned int* xw = (const unsigned int*)x;
  int lane = threadIdx.x;
  int cnt = 0;
  #pragma unroll
  for (int i = 0; i < 16; i++){
    unsigned int w = xw[lane * 16 + i];
    unsigned int e = (w >> 7) & 0xFFu;           // exponent of LOW bf16 half
    cnt += (e >= 100u && e <= 140u) ? 1 : 0;
  }
  #pragma unroll
  for (int off = 32; off; off >>= 1) cnt += __shfl_down(cnt, off);
  if (lane == 0){
    int flag = (cnt >= 700) ? 1 : 0;             // bf16 ~1014/1024; f32 ~165/1024
    float t0, t1;
    if (flag){
      t0 = __bfloat162float(((const __hip_bfloat16*)t_span)[0]);
      t1 = __bfloat162float(((const __hip_bfloat16*)t_span)[1]);
    } else {
      t0 = ((const float*)t_span)[0];
      t1 = ((const float*)t_span)[1];
    }
    ws[WS_FLAG] = (float)flag;
    ws[WS_DT] = (t1 - t0) / (float)NSTEPS;
  }
}

// ---------------- kernel 0: weight convert into canonical ws forms ---------
__global__ void k0_convert(const void* __restrict__ conv_w, const void* __restrict__ conv_b,
                           const void* __restrict__ enc1_w, const void* __restrict__ enc1_b,
                           const void* __restrict__ enc2_w, const void* __restrict__ enc2_b,
                           const void* __restrict__ ode1_w, const void* __restrict__ ode1_b,
                           const void* __restrict__ ode2_w, const void* __restrict__ ode2_b,
                           const void* __restrict__ reg1_w, const void* __restrict__ reg1_b,
                           const void* __restrict__ reg2_w, const void* __restrict__ reg2_b,
                           float* __restrict__ ws){
  const int flag = (int)ws[WS_FLAG];
  int t = blockIdx.x * 256 + threadIdx.x;
  int stride = gridDim.x * 256;

  #define RD(src, i) (flag ? __bfloat162float(((const __hip_bfloat16*)(src))[i]) \
                           : ((const float*)(src))[i])

  for (int i = t; i < NKER*72; i += stride){
    int o = i / 72, r = i % 72, dk = r / 24, c = r % 24;
    ws[WS_CW + i] = RD(conv_w, o*72 + c*3 + dk);
  }
  for (int i = t; i < NKER; i += stride) ws[WS_CB + i] = RD(conv_b, i);
  for (int i = t; i < 1440*ENC; i += stride){
    int k = i >> 7, j = i & 127;
    ws[WS_E1T + i] = RD(enc1_w, j*1440 + k);
  }
  for (int i = t; i < ENC; i += stride) ws[WS_E1B + i] = RD(enc1_b, i);
  for (int i = t; i < HID*ENC; i += stride) ws[WS_EW + i] = RD(enc2_w, i);
  for (int i = t; i < HID; i += stride) ws[WS_EB + i] = RD(enc2_b, i);

  // hi/lo bf16 splits for MFMA weights (row-major [n][k])
  unsigned short* w1h = (unsigned short*)(ws + WS_W1H);
  unsigned short* w1l = (unsigned short*)(ws + WS_W1L);
  unsigned short* w2h = (unsigned short*)(ws + WS_W2H);
  unsigned short* w2l = (unsigned short*)(ws + WS_W2L);
  unsigned short* r1h = (unsigned short*)(ws + WS_R1H);
  unsigned short* r1l = (unsigned short*)(ws + WS_R1L);
  for (int i = t; i < HID*HID; i += stride){
    float w = RD(ode1_w, i);
    unsigned short h = f2bf(w);
    w1h[i] = h; w1l[i] = f2bf(w - bf2f(h));
    w = RD(ode2_w, i);
    h = f2bf(w);
    w2h[i] = h; w2l[i] = f2bf(w - bf2f(h));
  }
  for (int i = t; i < 32*HID; i += stride){
    float w = RD(reg1_w, i);
    unsigned short h = f2bf(w);
    r1h[i] = h; r1l[i] = f2bf(w - bf2f(h));
  }
  for (int i = t; i < HID; i += stride){
    ws[WS_O1B + i] = RD(ode1_b, i);
    ws[WS_O2B + i] = RD(ode2_b, i);
  }
  for (int i = t; i < 32; i += stride){
    ws[WS_R1B + i] = RD(reg1_b, i);
    ws[WS_R2W + i] = RD(reg2_w, i);
  }
  for (int i = t; i < 1; i += stride) ws[WS_R2B + i] = RD(reg2_b, i);
  #undef RD
}

// ---------------- kernel 1: conv+silu+enc1+relu+enc2 -> theta0 -------------
__launch_bounds__(256, 2)
__global__ void k1_encoder(const void* __restrict__ x,
                           const float* __restrict__ ws,
                           float* __restrict__ theta0){
  const int flag = (int)ws[WS_FLAG];
  const int b = blockIdx.x * 256 + threadIdx.x;
  const float* CW  = ws + WS_CW;
  const float* CB  = ws + WS_CB;
  const float* E1T = ws + WS_E1T;

  float e1[ENC];
  #pragma unroll
  for (int j = 0; j < ENC; j++) e1[j] = 0.0f;

  #pragma unroll 1
  for (int s = 0; s < SEQ; s++){
    float xw[3 * IN_DIM];
    #pragma unroll
    for (int dk = 0; dk < 3; dk++){
      int sr = s + dk - 1;
      if (sr >= 0 && sr < SEQ){
        if (flag){
          const __hip_bfloat16* xrow = (const __hip_bfloat16*)x + (long)b * (SEQ*IN_DIM);
          const uint4* px = (const uint4*)(xrow + sr * IN_DIM);
          uint4 u0 = px[0], u1 = px[1], u2 = px[2];
          unsigned int uu[12] = {u0.x,u0.y,u0.z,u0.w, u1.x,u1.y,u1.z,u1.w, u2.x,u2.y,u2.z,u2.w};
          #pragma unroll
          for (int w = 0; w < 12; w++){
            xw[dk*24 + 2*w]     = bflo(uu[w]);
            xw[dk*24 + 2*w + 1] = bfhi(uu[w]);
          }
        } else {
          const float* xrow = (const float*)x + (long)b * (SEQ*IN_DIM);
          const float4* px = (const float4*)(xrow + sr * IN_DIM);
          #pragma unroll
          for (int w = 0; w < 6; w++){
            float4 v = px[w];
            xw[dk*24 + 4*w]     = v.x;
            xw[dk*24 + 4*w + 1] = v.y;
            xw[dk*24 + 4*w + 2] = v.z;
            xw[dk*24 + 4*w + 3] = v.w;
          }
        }
      } else {
        #pragma unroll
        for (int c = 0; c < 24; c++) xw[dk*24 + c] = 0.0f;
      }
    }
    #pragma unroll 1
    for (int o = 0; o < NKER; o++){
      const float* cw = CW + o*72;
      float acc = CB[o];
      #pragma unroll
      for (int i2 = 0; i2 < 72; i2++) acc += cw[i2] * xw[i2];
      float av = acc * __builtin_amdgcn_rcpf(1.0f + __expf(-acc));   // SiLU
      const float* wrow = E1T + (o*SEQ + s) * ENC;
      #pragma unroll
      for (int j = 0; j < ENC; j++) e1[j] += av * wrow[j];
    }
  }
  const float* E1B = ws + WS_E1B;
  #pragma unroll
  for (int j = 0; j < ENC; j++){
    float v = e1[j] + E1B[j];
    e1[j] = v > 0.0f ? v : 0.0f;
  }
  const float* EW = ws + WS_EW;
  const float* EB = ws + WS_EB;
  float* th = theta0 + (long)b * HID;
  #pragma unroll 1
  for (int n = 0; n < HID; n++){
    const float* wr = EW + n*ENC;
    float acc = EB[n];
    #pragma unroll
    for (int k = 0; k < ENC; k++) acc += wr[k] * e1[k];
    th[n] = acc;
  }
}

// ---------------- kernel 2: 50 dopri5 steps (split-bf16 MFMA) + regressor --
// one wave/block, 16 batch rows/wave.
// C/D layout: elem (m,n): n = nt*16 + (lane&15), m = (lane>>4)*4 + r
// A layout:   A[m][k]: m = lane&15, k = kc*32 + (lane>>4)*8 + j
// B layout:   B[k][n]: n = lane&15, k = kc*32 + (lane>>4)*8 + j
// LDS tile stored TRANSPOSED: tile[k*17 + m] (f32) -> all reads/writes
// bank-conflict-free (verified: write bank=17l+4q+C, read bank=8q+l+C).
__launch_bounds__(64, 1)
__global__ void k2_ode(const float* __restrict__ ws,
                       float* __restrict__ out){
  __shared__ float tile[64 * 17];
  const int tid = threadIdx.x;
  const int l = tid & 15, q = tid >> 4;
  const int rowbase = blockIdx.x * 16;
  const float* theta0 = ws + WS_TH0;

  // B-fragments hi+lo for W1, W2 (live in VGPRs for the whole kernel)
  short8 w1h[2][4], w1l[2][4], w2h[2][4], w2l[2][4];
  {
    const short8* p1h = (const short8*)(ws + WS_W1H);
    const short8* p1l = (const short8*)(ws + WS_W1L);
    const short8* p2h = (const short8*)(ws + WS_W2H);
    const short8* p2l = (const short8*)(ws + WS_W2L);
    #pragma unroll
    for (int nt = 0; nt < 4; nt++){
      int n = nt*16 + l;
      #pragma unroll
      for (int kc = 0; kc < 2; kc++){
        int idx = n*8 + kc*4 + q;
        w1h[kc][nt] = p1h[idx];
        w1l[kc][nt] = p1l[idx];
        w2h[kc][nt] = p2h[idx];
        w2l[kc][nt] = p2l[idx];
      }
    }
  }
  float b1v[4], b2v[4];
  #pragma unroll
  for (int nt = 0; nt < 4; nt++){
    b1v[nt] = ws[WS_O1B + nt*16 + l];
    b2v[nt] = ws[WS_O2B + nt*16 + l];
  }
  float dt = ws[WS_DT];

  float y[16];
  #pragma unroll
  for (int i = 0; i < 16; i++){
    int nt = i >> 2, r = i & 3;
    y[i] = theta0[(long)(rowbase + q*4 + r) * HID + nt*16 + l];
  }

  // write f32 C/D-layout values into the transposed tile
  auto put_tile = [&](const float* v){
    __syncthreads();
    #pragma unroll
    for (int i = 0; i < 16; i++){
      int nt = i >> 2, r = i & 3;
      tile[(nt*16 + l)*17 + q*4 + r] = v[i];
    }
    __syncthreads();
  };
  // read this lane's A-row (16 f32) and split into hi/lo bf16 frags
  auto get_frags = [&](short8& a0h, short8& a1h, short8& a0l, short8& a1l){
    union { short s[8]; short8 v; } u0h, u1h, u0l, u1l;
    #pragma unroll
    for (int j = 0; j < 8; j++){
      float v0 = tile[(q*8 + j)*17 + l];
      float v1 = tile[(q*8 + j + 32)*17 + l];
      unsigned short h0 = f2bf(v0);
      unsigned short h1 = f2bf(v1);
      u0h.s[j] = (short)h0; u0l.s[j] = (short)f2bf(v0 - bf2f(h0));
      u1h.s[j] = (short)h1; u1l.s[j] = (short)f2bf(v1 - bf2f(h1));
    }
    a0h = u0h.v; a1h = u1h.v; a0l = u0l.v; a1l = u1l.v;
  };

  auto feval = [&](const float* v, float* kk){
    short8 a0h, a1h, a0l, a1l;
    put_tile(v);
    get_frags(a0h, a1h, a0l, a1l);
    f32x4 hh[4];
    #pragma unroll
    for (int nt = 0; nt < 4; nt++){
      f32x4 c = {0.f, 0.f, 0.f, 0.f};
      c = __builtin_amdgcn_mfma_f32_16x16x32_bf16(a0h, w1h[0][nt], c, 0, 0, 0);
      c = __builtin_amdgcn_mfma_f32_16x16x32_bf16(a1h, w1h[1][nt], c, 0, 0, 0);
      c = __builtin_amdgcn_mfma_f32_16x16x32_bf16(a0l, w1h[0][nt], c, 0, 0, 0);
      c = __builtin_amdgcn_mfma_f32_16x16x32_bf16(a1l, w1h[1][nt], c, 0, 0, 0);
      c = __builtin_amdgcn_mfma_f32_16x16x32_bf16(a0h, w1l[0][nt], c, 0, 0, 0);
      c = __builtin_amdgcn_mfma_f32_16x16x32_bf16(a1h, w1l[1][nt], c, 0, 0, 0);
      hh[nt] = c;
    }
    float tv[16];
    #pragma unroll
    for (int nt = 0; nt < 4; nt++){
      #pragma unroll
      for (int r = 0; r < 4; r++) tv[nt*4 + r] = tanh_fast(hh[nt][r] + b1v[nt]);
    }
    put_tile(tv);
    get_frags(a0h, a1h, a0l, a1l);
    #pragma unroll
    for (int nt = 0; nt < 4; nt++){
      f32x4 c = {0.f, 0.f, 0.f, 0.f};
      c = __builtin_amdgcn_mfma_f32_16x16x32_bf16(a0h, w2h[0][nt], c, 0, 0, 0);
      c = __builtin_amdgcn_mfma_f32_16x16x32_bf16(a1h, w2h[1][nt], c, 0, 0, 0);
      c = __builtin_amdgcn_mfma_f32_16x16x32_bf16(a0l, w2h[0][nt], c, 0, 0, 0);
      c = __builtin_amdgcn_mfma_f32_16x16x32_bf16(a1l, w2h[1][nt], c, 0, 0, 0);
      c = __builtin_amdgcn_mfma_f32_16x16x32_bf16(a0h, w2l[0][nt], c, 0, 0, 0);
      c = __builtin_amdgcn_mfma_f32_16x16x32_bf16(a1h, w2l[1][nt], c, 0, 0, 0);
      #pragma unroll
      for (int r = 0; r < 4; r++) kk[nt*4 + r] = c[r] + b2v[nt];
    }
  };

  const float c21 = dt * 0.2f;
  const float c31 = dt * (3.0f/40.0f),     c32 = dt * (9.0f/40.0f);
  const float c41 = dt * (44.0f/45.0f),    c42 = dt * (-56.0f/15.0f),    c43 = dt * (32.0f/9.0f);
  const float c51 = dt * (19372.0f/6561.0f), c52 = dt * (-25360.0f/2187.0f),
              c53 = dt * (64448.0f/6561.0f), c54 = dt * (-212.0f/729.0f);
  const float c61 = dt * (9017.0f/3168.0f), c62 = dt * (-355.0f/33.0f),
              c63 = dt * (46732.0f/5247.0f), c64 = dt * (49.0f/176.0f),
              c65 = dt * (-5103.0f/18656.0f);
  const float d1 = dt * (35.0f/384.0f), d3 = dt * (500.0f/1113.0f), d4 = dt * (125.0f/192.0f),
              d5 = dt * (-2187.0f/6784.0f), d6 = dt * (11.0f/84.0f);

  float k1[16], k2[16], k3[16], k4[16], k5[16], k6[16], yt[16];

  #pragma unroll 1
  for (int st = 0; st < NSTEPS; st++){
    feval(y, k1);
    #pragma unroll
    for (int i = 0; i < 16; i++) yt[i] = y[i] + c21*k1[i];
    feval(yt, k2);
    #pragma unroll
    for (int i = 0; i < 16; i++) yt[i] = y[i] + c31*k1[i] + c32*k2[i];
    feval(yt, k3);
    #pragma unroll
    for (int i = 0; i < 16; i++) yt[i] = y[i] + c41*k1[i] + c42*k2[i] + c43*k3[i];
    feval(yt, k4);
    #pragma unroll
    for (int i = 0; i < 16; i++) yt[i] = y[i] + c51*k1[i] + c52*k2[i] + c53*k3[i] + c54*k4[i];
    feval(yt, k5);
    #pragma unroll
    for (int i = 0; i < 16; i++) yt[i] = y[i] + c61*k1[i] + c62*k2[i] + c63*k3[i] + c64*k4[i] + c65*k5[i];
    feval(yt, k6);
    #pragma unroll
    for (int i = 0; i < 16; i++) y[i] = y[i] + d1*k1[i] + d3*k3[i] + d4*k4[i] + d5*k5[i] + d6*k6[i];
  }

  // ---- regressor: relu(y @ reg1^T + b1) @ reg2^T + b2 ----
  {
    short8 a0h, a1h, a0l, a1l;
    put_tile(y);
    get_frags(a0h, a1h, a0l, a1l);
    const short8* prh = (const short8*)(ws + WS_R1H);
    const short8* prl = (const short8*)(ws + WS_R1L);
    float rr[2][4];
    #pragma unroll
    for (int nt = 0; nt < 2; nt++){
      int n = nt*16 + l;
      short8 bh0 = prh[n*8 + q];
      short8 bh1 = prh[n*8 + 4 + q];
      short8 bl0 = prl[n*8 + q];
      short8 bl1 = prl[n*8 + 4 + q];
      f32x4 c = {0.f, 0.f, 0.f, 0.f};
      c = __builtin_amdgcn_mfma_f32_16x16x32_bf16(a0h, bh0, c, 0, 0, 0);
      c = __builtin_amdgcn_mfma_f32_16x16x32_bf16(a1h, bh1, c, 0, 0, 0);
      c = __builtin_amdgcn_mfma_f32_16x16x32_bf16(a0l, bh0, c, 0, 0, 0);
      c = __builtin_amdgcn_mfma_f32_16x16x32_bf16(a1l, bh1, c, 0, 0, 0);
      c = __builtin_amdgcn_mfma_f32_16x16x32_bf16(a0h, bl0, c, 0, 0, 0);
      c = __builtin_amdgcn_mfma_f32_16x16x32_bf16(a1h, bl1, c, 0, 0, 0);
      float bias = ws[WS_R1B + n];
      #pragma unroll
      for (int r = 0; r < 4; r++){
        float v = c[r] + bias;
        rr[nt][r] = v > 0.0f ? v : 0.0f;
      }
    }
    float w2v0 = ws[WS_R2W + l];
    float w2v1 = ws[WS_R2W + 16 + l];
    float part[4];
    #pragma unroll
    for (int r = 0; r < 4; r++) part[r] = rr[0][r]*w2v0 + rr[1][r]*w2v1;
    #pragma unroll
    for (int off = 1; off < 16; off <<= 1){
      #pragma unroll
      for (int r = 0; r < 4; r++) part[r] += __shfl_xor(part[r], off);
    }
    float r2b = ws[WS_R2B];
    if (l == 0){
      #pragma unroll
      for (int r = 0; r < 4; r++)
        out[rowbase + q*4 + r] = part[r] + r2b;   // f32 output
    }
  }
}

// ---------------------------------------------------------------------------
extern "C" void kernel_launch(void* const* d_in, const int* in_sizes, int n_in,
                              void* d_out, int out_size, void* d_ws, size_t ws_size,
                              hipStream_t stream){
  (void)in_sizes; (void)n_in; (void)out_size; (void)ws_size;
  float* ws = (float*)d_ws;

  k_detect<<<dim3(1), dim3(64), 0, stream>>>(d_in[0], d_in[1], ws);
  k0_convert<<<dim3(64), dim3(256), 0, stream>>>(
      d_in[2], d_in[3], d_in[4], d_in[5], d_in[6], d_in[7],
      d_in[8], d_in[9], d_in[10], d_in[11], d_in[12], d_in[13],
      d_in[14], d_in[15], ws);
  k1_encoder<<<dim3(BTOT/256), dim3(256), 0, stream>>>(d_in[0], ws, ws + WS_TH0);
  k2_ode<<<dim3(BTOT/16), dim3(64), 0, stream>>>(ws, (float*)d_out);
}

// Round 4
// 2833.574 us; speedup vs baseline: 1.2766x; 1.2766x over previous
//
#include <hip/hip_runtime.h>
#include <hip/hip_bf16.h>

typedef __attribute__((ext_vector_type(8))) short short8;
typedef __attribute__((ext_vector_type(4))) float f32x4;

#define SEQ 40
#define IN_DIM 24
#define NKER 36
#define ENC 128
#define HID 64
#define NSTEPS 50
#define BTOT 65536

// ---- ws float-element offsets ----
#define WS_FLAG 0
#define WS_DT   1
#define WS_CW   16        // [36][3][24] f32
#define WS_CB   2608      // [36]
#define WS_E1B  2644      // [128]
#define WS_B1   2772      // [64]  ode1_b
#define WS_CZ   2836      // [64]  W1*b2
#define WS_CB2  2900      // [32]  T*reg1*b2 + reg1_b
#define WS_R2W  2932      // [32]
#define WS_R2B  2964      // [1]
#define WS_EBZ  2976      // [64]  W1*enc2_b
#define WS_PB   3040      // [32]  reg1*enc2_b
#define WS_E1T  4096      // [1440][128] f32 (enc1_w transposed)
#define WS_EWZ  188416    // [64][128] f32 = W1*enc2_w
#define WS_PW   196608    // [32][128] f32 = reg1*enc2_w
#define WS_MZH  200704    // [64][64] bf16 hi (2048 f)
#define WS_MZL  202752    // [64][64] bf16 lo
#define WS_QH   204800    // [32][64] bf16 hi (1024 f)
#define WS_QL   205824    // [32][64] bf16 lo
#define WS_ZP0  262144    // [B][96] f32: z0[64] + p0[32] per row

__device__ __forceinline__ unsigned short f2bf(float f){   // RNE
  union { float f; unsigned int u; } v; v.f = f;
  unsigned int r = (v.u + 0x7FFFu + ((v.u >> 16) & 1u)) >> 16;
  return (unsigned short)r;
}
__device__ __forceinline__ float bf2f(unsigned short s){
  union { unsigned int u; float f; } v; v.u = ((unsigned int)s) << 16; return v.f;
}
__device__ __forceinline__ float tanh_fast(float x){
  float ax = fabsf(x);
  float e  = __expf(-2.0f * ax);
  float t  = (1.0f - e) * __builtin_amdgcn_rcpf(1.0f + e);
  union { float f; unsigned int u; } vx, vt;
  vx.f = x; vt.f = t; vt.u |= (vx.u & 0x80000000u);
  return vt.f;
}

// ---------------- detector ----------------
__global__ void k_detect(const void* __restrict__ x, const void* __restrict__ t_span,
                         float* __restrict__ ws){
  const unsigned int* xw = (const unsigned int*)x;
  int lane = threadIdx.x;
  int cnt = 0;
  #pragma unroll
  for (int i = 0; i < 16; i++){
    unsigned int w = xw[lane * 16 + i];
    unsigned int e = (w >> 7) & 0xFFu;
    cnt += (e >= 100u && e <= 140u) ? 1 : 0;
  }
  #pragma unroll
  for (int off = 32; off; off >>= 1) cnt += __shfl_down(cnt, off);
  if (lane == 0){
    int flag = (cnt >= 700) ? 1 : 0;
    float t0, t1;
    if (flag){
      t0 = __bfloat162float(((const __hip_bfloat16*)t_span)[0]);
      t1 = __bfloat162float(((const __hip_bfloat16*)t_span)[1]);
    } else {
      t0 = ((const float*)t_span)[0];
      t1 = ((const float*)t_span)[1];
    }
    ws[WS_FLAG] = (float)flag;
    ws[WS_DT] = (t1 - t0) / (float)NSTEPS;
  }
}

// ---------------- k0: weight convert + algebraic folds ----------------
__global__ void k0_convert(const void* __restrict__ conv_w, const void* __restrict__ conv_b,
                           const void* __restrict__ enc1_w, const void* __restrict__ enc1_b,
                           const void* __restrict__ enc2_w, const void* __restrict__ enc2_b,
                           const void* __restrict__ ode1_w, const void* __restrict__ ode1_b,
                           const void* __restrict__ ode2_w, const void* __restrict__ ode2_b,
                           const void* __restrict__ reg1_w, const void* __restrict__ reg1_b,
                           const void* __restrict__ reg2_w, const void* __restrict__ reg2_b,
                           float* __restrict__ ws){
  const int flag = (int)ws[WS_FLAG];
  const float T = ws[WS_DT] * (float)NSTEPS;
  int t = blockIdx.x * 256 + threadIdx.x;
  int stride = gridDim.x * 256;

  #define RD(src, i) (flag ? __bfloat162float(((const __hip_bfloat16*)(src))[i]) \
                           : ((const float*)(src))[i])

  for (int i = t; i < NKER*72; i += stride){
    int o = i / 72, r = i % 72, dk = r / 24, c = r % 24;
    ws[WS_CW + i] = RD(conv_w, o*72 + c*3 + dk);
  }
  for (int i = t; i < NKER; i += stride) ws[WS_CB + i] = RD(conv_b, i);
  for (int i = t; i < 1440*ENC; i += stride){
    int k = i >> 7, j = i & 127;
    ws[WS_E1T + i] = RD(enc1_w, j*1440 + k);
  }
  for (int i = t; i < ENC; i += stride) ws[WS_E1B + i] = RD(enc1_b, i);

  // EWZ = W1 * enc2_w  [64][128]
  for (int i = t; i < 64*128; i += stride){
    int n = i >> 7, j = i & 127;
    float acc = 0.f;
    for (int h = 0; h < 64; h++) acc += RD(ode1_w, n*64+h) * RD(enc2_w, h*128+j);
    ws[WS_EWZ + i] = acc;
  }
  // PW = reg1 * enc2_w  [32][128]
  for (int i = t; i < 32*128; i += stride){
    int p = i >> 7, j = i & 127;
    float acc = 0.f;
    for (int h = 0; h < 64; h++) acc += RD(reg1_w, p*64+h) * RD(enc2_w, h*128+j);
    ws[WS_PW + i] = acc;
  }
  for (int i = t; i < 64; i += stride){
    float acc = 0.f;
    for (int h = 0; h < 64; h++) acc += RD(ode1_w, i*64+h) * RD(enc2_b, h);
    ws[WS_EBZ + i] = acc;
    float acc2 = 0.f;
    for (int h = 0; h < 64; h++) acc2 += RD(ode1_w, i*64+h) * RD(ode2_b, h);
    ws[WS_CZ + i] = acc2;
    ws[WS_B1 + i] = RD(ode1_b, i);
  }
  for (int i = t; i < 32; i += stride){
    float acc = 0.f;
    for (int h = 0; h < 64; h++) acc += RD(reg1_w, i*64+h) * RD(enc2_b, h);
    ws[WS_PB + i] = acc;
    float acc2 = 0.f;
    for (int h = 0; h < 64; h++) acc2 += RD(reg1_w, i*64+h) * RD(ode2_b, h);
    ws[WS_CB2 + i] = T * acc2 + RD(reg1_b, i);
    ws[WS_R2W + i] = RD(reg2_w, i);
  }
  if (t == 0) ws[WS_R2B] = RD(reg2_b, 0);

  // Mz = W1*W2 [64][64], split hi/lo bf16
  unsigned short* mzh = (unsigned short*)(ws + WS_MZH);
  unsigned short* mzl = (unsigned short*)(ws + WS_MZL);
  for (int i = t; i < 64*64; i += stride){
    int a = i >> 6, b = i & 63;
    float acc = 0.f;
    for (int h = 0; h < 64; h++) acc += RD(ode1_w, a*64+h) * RD(ode2_w, h*64+b);
    unsigned short hi = f2bf(acc);
    mzh[i] = hi; mzl[i] = f2bf(acc - bf2f(hi));
  }
  // Q = reg1*W2 [32][64], split hi/lo bf16
  unsigned short* qh = (unsigned short*)(ws + WS_QH);
  unsigned short* ql = (unsigned short*)(ws + WS_QL);
  for (int i = t; i < 32*64; i += stride){
    int p = i >> 6, b = i & 63;
    float acc = 0.f;
    for (int h = 0; h < 64; h++) acc += RD(reg1_w, p*64+h) * RD(ode2_w, h*64+b);
    unsigned short hi = f2bf(acc);
    qh[i] = hi; ql[i] = f2bf(acc - bf2f(hi));
  }
  #undef RD
}

// ---------------- k1: conv+silu+enc1+relu -> z0,p0 ----------------
// 512 blocks x 256 thr; 128 rows/block; thread = (row_local = t&127, half h = t>>7)
// half h covers conv channels o in [18h, 18h+18)
__launch_bounds__(256, 2)
__global__ void k1_encoder(const void* __restrict__ x,
                           const float* __restrict__ ws,
                           float* __restrict__ zp0){
  __shared__ float lds[16384];   // 64 KB, reused in 3 phases
  const int flag = (int)ws[WS_FLAG];
  const int t = threadIdx.x;
  const int r_loc = t & 127, h = t >> 7;
  const long row = (long)blockIdx.x * 128 + r_loc;

  float e1[ENC];
  #pragma unroll
  for (int j = 0; j < ENC; j++) e1[j] = 0.0f;

  float xa[24], xb[24], xc[24];

  auto loadcol = [&](float* dst, int col){
    if (col >= 0 && col < SEQ){
      if (flag){
        const __hip_bfloat16* xp = (const __hip_bfloat16*)x + row*(SEQ*IN_DIM) + col*IN_DIM;
        const uint4* px = (const uint4*)xp;
        #pragma unroll
        for (int w = 0; w < 3; w++){
          uint4 u = px[w];
          unsigned int uu[4] = {u.x,u.y,u.z,u.w};
          #pragma unroll
          for (int e = 0; e < 4; e++){
            union { unsigned int i; float f; } lo, hi;
            lo.i = uu[e] << 16; hi.i = uu[e] & 0xffff0000u;
            dst[w*8 + 2*e] = lo.f; dst[w*8 + 2*e + 1] = hi.f;
          }
        }
      } else {
        const float* xp = (const float*)x + row*(SEQ*IN_DIM) + col*IN_DIM;
        const float4* px = (const float4*)xp;
        #pragma unroll
        for (int w = 0; w < 6; w++){
          float4 v = px[w];
          dst[4*w] = v.x; dst[4*w+1] = v.y; dst[4*w+2] = v.z; dst[4*w+3] = v.w;
        }
      }
    } else {
      #pragma unroll
      for (int c = 0; c < 24; c++) dst[c] = 0.0f;
    }
  };

  const float* CW = ws + WS_CW;
  const float* CB = ws + WS_CB;

  auto iter = [&](int s, float* xm1, float* x0, float* xp1){
    // stage enc1 weight slice for this s: 36 rows x 128 f32
    __syncthreads();
    for (int idx = t; idx < 36*32; idx += 256){
      int o = idx >> 5, j4 = idx & 31;
      float4 v = *(const float4*)(ws + WS_E1T + (o*SEQ + s)*ENC + j4*4);
      *(float4*)(lds + o*ENC + j4*4) = v;
    }
    __syncthreads();
    #pragma unroll 1
    for (int oo = 0; oo < 18; oo++){
      int o = h*18 + oo;
      const float* w = CW + o*72;
      float acc = CB[o];
      #pragma unroll
      for (int c = 0; c < 24; c++) acc += w[c] * xm1[c];
      #pragma unroll
      for (int c = 0; c < 24; c++) acc += w[24+c] * x0[c];
      #pragma unroll
      for (int c = 0; c < 24; c++) acc += w[48+c] * xp1[c];
      float av = acc * __builtin_amdgcn_rcpf(1.0f + __expf(-acc));  // SiLU
      const float* wrow = lds + o*ENC;
      #pragma unroll
      for (int j = 0; j < ENC; j++) e1[j] += av * wrow[j];
    }
    loadcol(xm1, s + 2);   // xm1 freed; becomes col s+2 for iter s+1
  };

  // prologue
  #pragma unroll
  for (int c = 0; c < 24; c++) xa[c] = 0.0f;   // col -1
  loadcol(xb, 0);
  loadcol(xc, 1);

  #pragma unroll 1
  for (int st = 0; st < 39; st += 3){
    iter(st,     xa, xb, xc);
    iter(st + 1, xb, xc, xa);
    iter(st + 2, xc, xa, xb);
  }
  iter(39, xa, xb, xc);

  // ---- combine halves via LDS (rotation swizzle: conflict-free) ----
  __syncthreads();
  if (h == 1){
    #pragma unroll
    for (int j = 0; j < ENC; j++) lds[r_loc*128 + ((j + r_loc) & 127)] = e1[j];
  }
  __syncthreads();
  if (h == 0){
    const float* E1B = ws + WS_E1B;
    #pragma unroll
    for (int j = 0; j < ENC; j++){
      float v = e1[j] + lds[r_loc*128 + ((j + r_loc) & 127)] + E1B[j];
      e1[j] = v > 0.0f ? v : 0.0f;
    }
  }
  __syncthreads();   // before lds reuse
  // ---- folded enc2: z0 = EWZ*e1 + EBZ (64), p0 = PW*e1 + PB (32) ----
  if (h == 0){
    #pragma unroll 1
    for (int n = 0; n < 96; n++){
      const float* wr = (n < 64) ? (ws + WS_EWZ + n*ENC) : (ws + WS_PW + (n-64)*ENC);
      float acc = (n < 64) ? ws[WS_EBZ + n] : ws[WS_PB + (n-64)];
      #pragma unroll
      for (int k = 0; k < ENC; k++) acc += wr[k] * e1[k];
      lds[r_loc*97 + n] = acc;     // stride 97: bank = r+n mod 32, 2-way free
    }
  }
  __syncthreads();
  // coalesced global write of [128][96]
  float* dst = zp0 + (long)blockIdx.x * 128 * 96;
  #pragma unroll 1
  for (int idx = t; idx < 128*96; idx += 256){
    int r = idx / 96, n = idx - r*96;
    dst[idx] = lds[r*97 + n];
  }
}

// ---------------- k2: 50 dopri5 steps on z (split-bf16 MFMA) + regressor --
// one wave/block, 16 rows/wave. z' = Mz*tanh(z+b1) + cz ; s += dt*bw_i*u_i
// C/D: elem (m,n): n = nt*16+(lane&15), m = (lane>>4)*4 + r
// A:   A[m][k]: m = lane&15, k = kc*32 + (lane>>4)*8 + j
// LDS tile [k][m'] stride 17, m' = m ^ (8*((k>>2)&1))
__launch_bounds__(64, 2)
__global__ void k2_ode(const float* __restrict__ ws,
                       const float* __restrict__ zp0,
                       float* __restrict__ out){
  __shared__ float scr[64*17];
  const int tid = threadIdx.x;
  const int l = tid & 15, q = tid >> 4;
  const int sl8 = 8 * ((l >> 2) & 1);
  const int rowbase = blockIdx.x * 16;

  short8 mh[2][4], ml[2][4];
  {
    const short8* pmh = (const short8*)(ws + WS_MZH);
    const short8* pml = (const short8*)(ws + WS_MZL);
    #pragma unroll
    for (int nt = 0; nt < 4; nt++){
      int n = nt*16 + l;
      #pragma unroll
      for (int kc = 0; kc < 2; kc++){
        int idx = n*8 + kc*4 + q;
        mh[kc][nt] = pmh[idx];
        ml[kc][nt] = pml[idx];
      }
    }
  }
  float b1v[4], czv[4];
  #pragma unroll
  for (int nt = 0; nt < 4; nt++){
    b1v[nt] = ws[WS_B1 + nt*16 + l];
    czv[nt] = ws[WS_CZ + nt*16 + l];
  }
  const float dt = ws[WS_DT];

  float z[16], s[16];
  #pragma unroll
  for (int i = 0; i < 16; i++){
    int nt = i >> 2, r = i & 3;
    z[i] = zp0[(long)(rowbase + q*4 + r) * 96 + nt*16 + l];
    s[i] = 0.0f;
  }

  auto put_tile = [&](const float* u){
    __syncthreads();
    #pragma unroll
    for (int nt = 0; nt < 4; nt++){
      int base = (nt*16 + l)*17 + ((q*4) ^ sl8);
      scr[base+0] = u[nt*4+0];
      scr[base+1] = u[nt*4+1];
      scr[base+2] = u[nt*4+2];
      scr[base+3] = u[nt*4+3];
    }
    __syncthreads();
  };
  auto get_frags = [&](short8& a0h, short8& a1h, short8& a0l, short8& a1l){
    union { short sv[8]; short8 v; } u0h, u1h, u0l, u1l;
    #pragma unroll
    for (int j = 0; j < 8; j++){
      int mp = (j < 4) ? l : (l ^ 8);
      float v0 = scr[(q*8 + j)*17 + mp];
      float v1 = scr[(q*8 + j + 32)*17 + mp];
      unsigned short h0 = f2bf(v0);
      unsigned short h1 = f2bf(v1);
      u0h.sv[j] = (short)h0; u0l.sv[j] = (short)f2bf(v0 - bf2f(h0));
      u1h.sv[j] = (short)h1; u1l.sv[j] = (short)f2bf(v1 - bf2f(h1));
    }
    a0h = u0h.v; a1h = u1h.v; a0l = u0l.v; a1l = u1l.v;
  };

  auto feval = [&](const float* v, float* g, float w){
    float u[16];
    #pragma unroll
    for (int nt = 0; nt < 4; nt++){
      #pragma unroll
      for (int r = 0; r < 4; r++) u[nt*4+r] = tanh_fast(v[nt*4+r] + b1v[nt]);
    }
    if (w != 0.0f){
      #pragma unroll
      for (int i = 0; i < 16; i++) s[i] += w * u[i];
    }
    put_tile(u);
    short8 a0h, a1h, a0l, a1l;
    get_frags(a0h, a1h, a0l, a1l);
    #pragma unroll
    for (int nt = 0; nt < 4; nt++){
      f32x4 c = {0.f, 0.f, 0.f, 0.f};
      c = __builtin_amdgcn_mfma_f32_16x16x32_bf16(a0h, mh[0][nt], c, 0, 0, 0);
      c = __builtin_amdgcn_mfma_f32_16x16x32_bf16(a1h, mh[1][nt], c, 0, 0, 0);
      c = __builtin_amdgcn_mfma_f32_16x16x32_bf16(a0l, mh[0][nt], c, 0, 0, 0);
      c = __builtin_amdgcn_mfma_f32_16x16x32_bf16(a1l, mh[1][nt], c, 0, 0, 0);
      c = __builtin_amdgcn_mfma_f32_16x16x32_bf16(a0h, ml[0][nt], c, 0, 0, 0);
      c = __builtin_amdgcn_mfma_f32_16x16x32_bf16(a1h, ml[1][nt], c, 0, 0, 0);
      #pragma unroll
      for (int r = 0; r < 4; r++) g[nt*4+r] = c[r] + czv[nt];
    }
  };

  const float c21 = dt * 0.2f;
  const float c31 = dt * (3.0f/40.0f),      c32 = dt * (9.0f/40.0f);
  const float c41 = dt * (44.0f/45.0f),     c42 = dt * (-56.0f/15.0f),   c43 = dt * (32.0f/9.0f);
  const float c51 = dt * (19372.0f/6561.0f), c52 = dt * (-25360.0f/2187.0f),
              c53 = dt * (64448.0f/6561.0f), c54 = dt * (-212.0f/729.0f);
  const float c61 = dt * (9017.0f/3168.0f),  c62 = dt * (-355.0f/33.0f),
              c63 = dt * (46732.0f/5247.0f), c64 = dt * (49.0f/176.0f),
              c65 = dt * (-5103.0f/18656.0f);
  const float d1 = dt * (35.0f/384.0f), d3 = dt * (500.0f/1113.0f), d4 = dt * (125.0f/192.0f),
              d5 = dt * (-2187.0f/6784.0f), d6 = dt * (11.0f/84.0f);

  float g1[16], g2[16], g3[16], g4[16], g5[16], g6[16], yt[16];

  #pragma unroll 1
  for (int st = 0; st < NSTEPS; st++){
    feval(z, g1, d1);
    #pragma unroll
    for (int i = 0; i < 16; i++) yt[i] = z[i] + c21*g1[i];
    feval(yt, g2, 0.0f);
    #pragma unroll
    for (int i = 0; i < 16; i++) yt[i] = z[i] + c31*g1[i] + c32*g2[i];
    feval(yt, g3, d3);
    #pragma unroll
    for (int i = 0; i < 16; i++) yt[i] = z[i] + c41*g1[i] + c42*g2[i] + c43*g3[i];
    feval(yt, g4, d4);
    #pragma unroll
    for (int i = 0; i < 16; i++) yt[i] = z[i] + c51*g1[i] + c52*g2[i] + c53*g3[i] + c54*g4[i];
    feval(yt, g5, d5);
    #pragma unroll
    for (int i = 0; i < 16; i++) yt[i] = z[i] + c61*g1[i] + c62*g2[i] + c63*g3[i] + c64*g4[i] + c65*g5[i];
    feval(yt, g6, d6);
    #pragma unroll
    for (int i = 0; i < 16; i++) z[i] = z[i] + d1*g1[i] + d3*g3[i] + d4*g4[i] + d5*g5[i] + d6*g6[i];
  }

  // ---- regressor: r = relu(p0 + Q*s + cb); out = reg2*r + r2b ----
  {
    put_tile(s);
    short8 a0h, a1h, a0l, a1l;
    get_frags(a0h, a1h, a0l, a1l);
    const short8* pqh = (const short8*)(ws + WS_QH);
    const short8* pql = (const short8*)(ws + WS_QL);
    float rr[2][4];
    #pragma unroll
    for (int nt2 = 0; nt2 < 2; nt2++){
      int n = nt2*16 + l;
      short8 qh0 = pqh[n*8 + q];
      short8 qh1 = pqh[n*8 + 4 + q];
      short8 ql0 = pql[n*8 + q];
      short8 ql1 = pql[n*8 + 4 + q];
      f32x4 c = {0.f, 0.f, 0.f, 0.f};
      c = __builtin_amdgcn_mfma_f32_16x16x32_bf16(a0h, qh0, c, 0, 0, 0);
      c = __builtin_amdgcn_mfma_f32_16x16x32_bf16(a1h, qh1, c, 0, 0, 0);
      c = __builtin_amdgcn_mfma_f32_16x16x32_bf16(a0l, qh0, c, 0, 0, 0);
      c = __builtin_amdgcn_mfma_f32_16x16x32_bf16(a1l, qh1, c, 0, 0, 0);
      c = __builtin_amdgcn_mfma_f32_16x16x32_bf16(a0h, ql0, c, 0, 0, 0);
      c = __builtin_amdgcn_mfma_f32_16x16x32_bf16(a1h, ql1, c, 0, 0, 0);
      float cbn = ws[WS_CB2 + n];
      #pragma unroll
      for (int r = 0; r < 4; r++){
        float p0 = zp0[(long)(rowbase + q*4 + r) * 96 + 64 + n];
        float v = c[r] + cbn + p0;
        rr[nt2][r] = v > 0.0f ? v : 0.0f;
      }
    }
    float w2v0 = ws[WS_R2W + l];
    float w2v1 = ws[WS_R2W + 16 + l];
    float part[4];
    #pragma unroll
    for (int r = 0; r < 4; r++) part[r] = rr[0][r]*w2v0 + rr[1][r]*w2v1;
    #pragma unroll
    for (int off = 1; off < 16; off <<= 1){
      #pragma unroll
      for (int r = 0; r < 4; r++) part[r] += __shfl_xor(part[r], off);
    }
    float r2b = ws[WS_R2B];
    if (l == 0){
      #pragma unroll
      for (int r = 0; r < 4; r++)
        out[rowbase + q*4 + r] = part[r] + r2b;
    }
  }
}

// ---------------------------------------------------------------------------
extern "C" void kernel_launch(void* const* d_in, const int* in_sizes, int n_in,
                              void* d_out, int out_size, void* d_ws, size_t ws_size,
                              hipStream_t stream){
  (void)in_sizes; (void)n_in; (void)out_size; (void)ws_size;
  float* ws = (float*)d_ws;

  k_detect<<<dim3(1), dim3(64), 0, stream>>>(d_in[0], d_in[1], ws);
  k0_convert<<<dim3(64), dim3(256), 0, stream>>>(
      d_in[2], d_in[3], d_in[4], d_in[5], d_in[6], d_in[7],
      d_in[8], d_in[9], d_in[10], d_in[11], d_in[12], d_in[13],
      d_in[14], d_in[15], ws);
  k1_encoder<<<dim3(BTOT/128), dim3(256), 0, stream>>>(d_in[0], ws, ws + WS_ZP0);
  k2_ode<<<dim3(BTOT/16), dim3(64), 0, stream>>>(ws, ws + WS_ZP0, (float*)d_out);
}